// Round 5
// baseline (288.451 us; speedup 1.0000x reference)
//
#include <hip/hip_runtime.h>
#include <hip/hip_bf16.h>
#include <stdint.h>

typedef __attribute__((ext_vector_type(4))) float f32x4;
typedef __attribute__((ext_vector_type(8))) short s16x8;
typedef __attribute__((ext_vector_type(4))) short s16x4;

#define B_   2
#define S_   2048
#define D_   1024
#define H_   16
#define HS_  64
#define TOK  (B_*S_)   // 4096
#define BH_  (B_*H_)   // 32

__device__ __forceinline__ short f2bf(float f){
  union { float f; uint32_t u; } v; v.f = f;
  uint32_t u = v.u;
  u += 0x7fffu + ((u >> 16) & 1u);   // round-to-nearest-even
  return (short)(u >> 16);
}

__device__ __forceinline__ uint32_t cvt_pk_bf16(float lo, float hi){
  uint32_t r;
  asm("v_cvt_pk_bf16_f32 %0, %1, %2" : "=v"(r) : "v"(lo), "v"(hi));
  return r;
}

__device__ __forceinline__ void gload_lds16(const void* g, void* l){
  __builtin_amdgcn_global_load_lds((const __attribute__((address_space(1))) void*)g,
                                   (__attribute__((address_space(3))) void*)l, 16, 0, 0);
}

// ---------------- fp32 -> bf16 convert (vectorized) ----------------
__global__ void k_cvt(const float* __restrict__ src, short* __restrict__ dst, int n4){
  int i = blockIdx.x * blockDim.x + threadIdx.x;
  if (i < n4){
    float4 v = reinterpret_cast<const float4*>(src)[i];
    s16x4 o;
    o.x = f2bf(v.x); o.y = f2bf(v.y); o.z = f2bf(v.z); o.w = f2bf(v.w);
    reinterpret_cast<s16x4*>(dst)[i] = o;
  }
}

// ---------------- transpose + convert: src[K][N] f32 -> dst[N][K] bf16 ----------------
__global__ void k_tconv(const float* __restrict__ src, short* __restrict__ dst, int K, int N){
  __shared__ short tile[32][33];
  const int n0 = blockIdx.x * 32, k0 = blockIdx.y * 32;
  const int c = threadIdx.x & 31, r8 = threadIdx.x >> 5;
  #pragma unroll
  for (int j = 0; j < 4; j++){
    int k = r8 + j * 8;
    tile[c][k] = f2bf(src[(size_t)(k0 + k) * N + n0 + c]);
  }
  __syncthreads();
  #pragma unroll
  for (int j = 0; j < 4; j++){
    int nl = r8 + j * 8;
    dst[(size_t)(n0 + nl) * K + k0 + c] = tile[nl][c];
  }
}

// ---------------- bf16 GEMM, 128x128 tile, BK=32, K=1024 fixed ----------------
template<int EPI>
__global__ __launch_bounds__(256, 2) void k_gemm(
    const short* __restrict__ A, const short* __restrict__ Bt,
    const float* __restrict__ bias, void* __restrict__ outp)
{
  __shared__ short Al[128 * 32];
  __shared__ short Bl[128 * 32];
  const int tid = threadIdx.x;
  const int lane = tid & 63, wave = tid >> 6;
  const int m0 = blockIdx.x * 128, n0 = blockIdx.y * 128;
  const int wm = (wave >> 1) * 64, wn = (wave & 1) * 64;
  const int c = lane & 15, g = lane >> 4;

  f32x4 acc[4][4];
  #pragma unroll
  for (int i = 0; i < 4; i++)
    #pragma unroll
    for (int j = 0; j < 4; j++) acc[i][j] = (f32x4){0.f, 0.f, 0.f, 0.f};

  const short* Asrc = A + (size_t)m0 * 1024;
  const short* Bsrc = Bt + (size_t)n0 * 1024;

  for (int kt = 0; kt < 1024; kt += 32){
    __syncthreads();
    #pragma unroll
    for (int j = 0; j < 2; j++){
      int gc = (wave * 2 + j) * 64 + lane;
      int row = gc >> 2, c8 = gc & 3;
      gload_lds16(Asrc + (size_t)row * 1024 + kt + c8 * 8, Al + (size_t)(wave * 2 + j) * 512);
      gload_lds16(Bsrc + (size_t)row * 1024 + kt + c8 * 8, Bl + (size_t)(wave * 2 + j) * 512);
    }
    __syncthreads();

    s16x8 af[4], bq[4];
    #pragma unroll
    for (int t = 0; t < 4; t++){
      af[t] = *(const s16x8*)&Al[(wm + t * 16 + c) * 32 + g * 8];
      bq[t] = *(const s16x8*)&Bl[(wn + t * 16 + c) * 32 + g * 8];
    }
    #pragma unroll
    for (int mt = 0; mt < 4; mt++)
      #pragma unroll
      for (int nt = 0; nt < 4; nt++)
        acc[mt][nt] = __builtin_amdgcn_mfma_f32_16x16x32_bf16(af[mt], bq[nt], acc[mt][nt], 0, 0, 0);
  }

  if (EPI == 0){
    short* Qb = (short*)outp;
    const size_t QSZ = (size_t)BH_ * S_ * HS_;
    #pragma unroll
    for (int mt = 0; mt < 4; mt++){
      #pragma unroll
      for (int nt = 0; nt < 4; nt++){
        int n = n0 + wn + nt * 16 + c;
        float bv = bias[n];
        int sel = n >> 10, hn = (n >> 6) & 15, d = n & 63;
        #pragma unroll
        for (int r = 0; r < 4; r++){
          int token = m0 + wm + mt * 16 + g * 4 + r;
          int b = token >> 11, s = token & 2047;
          float v = acc[mt][nt][r] + bv;
          Qb[(size_t)sel * QSZ + ((size_t)(b * H_ + hn) * S_ + s) * HS_ + d] = f2bf(v);
        }
      }
    }
  } else {
    float* O = (float*)outp;
    #pragma unroll
    for (int mt = 0; mt < 4; mt++){
      #pragma unroll
      for (int nt = 0; nt < 4; nt++){
        int n = n0 + wn + nt * 16 + c;
        float bv = bias[n];
        #pragma unroll
        for (int r = 0; r < 4; r++){
          int token = m0 + wm + mt * 16 + g * 4 + r;
          O[(size_t)token * 1024 + n] = acc[mt][nt][r] + bv;
        }
      }
    }
  }
}

// ---------------- V [bh][s][64] -> Vt [bh][64][s] (bf16) ----------------
__global__ void k_vtrans(const short* __restrict__ Vg, short* __restrict__ Vt){
  __shared__ short t[64 * 80];
  const int bh = blockIdx.y;
  const int s0 = blockIdx.x * 64;
  const int tid = threadIdx.x;
  const int r = tid >> 3, c8 = (tid & 7) * 8;
  #pragma unroll
  for (int p = 0; p < 2; p++){
    int ss = r + p * 32;
    s16x8 v = *(const s16x8*)&Vg[((size_t)bh * S_ + s0 + ss) * HS_ + c8];
    #pragma unroll
    for (int i = 0; i < 8; i++) t[(c8 + i) * 80 + ss] = v[i];
  }
  __syncthreads();
  #pragma unroll
  for (int p = 0; p < 2; p++){
    int d = r + p * 32;
    s16x8 v = *(const s16x8*)&t[d * 80 + c8];
    *(s16x8*)&Vt[((size_t)bh * HS_ + d) * S_ + s0 + c8] = v;
  }
}

// ---------------- causal flash attention: 4-way split-K, software-pipelined ----------------
// Block owns one 16-row q-tile; wave w handles k-tiles kt ≡ w (mod 4).
// K fragments ping-pong (kA/kB) prefetched one tile ahead; V issued at iter start
// (latency hidden under QK^T+softmax). sched_barrier(0) pins load placement so the
// register-pressure heuristic can't sink them (round-4 failure mode: VGPR=60).
__global__ __launch_bounds__(256, 3) void k_attn(
    const short* __restrict__ Qg, const short* __restrict__ Kg,
    const short* __restrict__ Vt, short* __restrict__ Og)
{
  __shared__ short Pl[4][16 * 64];   // per-wave P rows [q=c][kk], XOR-swizzled
  __shared__ float Mo[3][64][18];    // partial O from waves 1..3 (72B stride, 8B-aligned)
  __shared__ float Ml[3][16];
  __shared__ float Ll[3][16];
  __shared__ float Fq[4][16];
  __shared__ float Linv[16];

  const int tid = threadIdx.x, lane = tid & 63, wave = tid >> 6;
  const int c = lane & 15, g = lane >> 4;
  const int p = blockIdx.x;
  const int xcd = p & 7, j = p >> 3;
  const int bh = xcd * 4 + (j & 3);
  const int qt16 = 127 - (j >> 2);         // descending: long tiles first
  const int q0 = qt16 * 16;
  const int nkt = (qt16 >> 2) + 1;
  const size_t basebh = (size_t)bh * S_ * HS_;
  const short* Kb  = Kg + basebh;
  const short* Vtb = Vt + (size_t)bh * HS_ * S_;

  s16x8 qb0, qb1;
  {
    const short* qp = Qg + basebh + (size_t)(q0 + c) * HS_ + g * 8;
    qb0 = *(const s16x8*)qp;
    qb1 = *(const s16x8*)(qp + 32);
  }
  f32x4 o_acc[4];
  #pragma unroll
  for (int i = 0; i < 4; i++) o_acc[i] = (f32x4){0.f, 0.f, 0.f, 0.f};
  float m_c = -3e38f, l_c = 0.f;
  short* Pw = &Pl[wave][0];
  const int swr = (c & 7) * 8;
  const float SC = 0.125f * 1.44269504f;   // scale * log2(e)

  s16x8 kA[8], kB[8], vC[8];

  auto loadK = [&](s16x8 (&kr)[8], int kt){
    const int k0 = kt * 64;
    #pragma unroll
    for (int nt = 0; nt < 4; nt++){
      const short* kp = Kb + (size_t)(k0 + nt * 16 + c) * HS_ + g * 8;
      kr[nt * 2]     = *(const s16x8*)kp;
      kr[nt * 2 + 1] = *(const s16x8*)(kp + 32);
    }
  };
  auto loadV = [&](int kt){
    const int k0 = kt * 64;
    #pragma unroll
    for (int nt = 0; nt < 4; nt++){
      const short* vp = Vtb + (size_t)(nt * 16 + c) * S_ + k0 + g * 8;
      vC[nt * 2]     = *(const s16x8*)vp;
      vC[nt * 2 + 1] = *(const s16x8*)(vp + 32);
    }
  };

  auto computeT = [&](s16x8 (&kr)[8], int kt){
    const int k0 = kt * 64;
    const bool diag = (kt == nkt - 1);

    // S^T = K * Q^T : st[nt][r] = S[q0+c][k0 + nt*16 + g*4 + r]
    f32x4 st[4];
    #pragma unroll
    for (int nt = 0; nt < 4; nt++){
      f32x4 a = (f32x4){0.f, 0.f, 0.f, 0.f};
      a = __builtin_amdgcn_mfma_f32_16x16x32_bf16(kr[nt * 2],     qb0, a, 0, 0, 0);
      a = __builtin_amdgcn_mfma_f32_16x16x32_bf16(kr[nt * 2 + 1], qb1, a, 0, 0, 0);
      st[nt] = a;
    }

    float sc[16];
    float tmax = -3e38f;
    #pragma unroll
    for (int nt = 0; nt < 4; nt++)
      #pragma unroll
      for (int r = 0; r < 4; r++){
        float v = st[nt][r] * SC;
        if (diag && (k0 + nt * 16 + g * 4 + r > q0 + c)) v = -3e38f;
        sc[nt * 4 + r] = v;
        tmax = fmaxf(tmax, v);
      }
    tmax = fmaxf(tmax, __shfl_xor(tmax, 16));
    tmax = fmaxf(tmax, __shfl_xor(tmax, 32));

    // T13: skip rescale when running max doesn't grow (wave-uniform)
    if (!__all(tmax <= m_c)){
      float mnew = fmaxf(m_c, tmax);
      float fe = exp2f(m_c - mnew);
      m_c = mnew;
      l_c *= fe;
      float feq[4];
      #pragma unroll
      for (int r = 0; r < 4; r++) feq[r] = __shfl(fe, g * 4 + r);
      #pragma unroll
      for (int nt = 0; nt < 4; nt++){
        f32x4 t = o_acc[nt];
        t[0] *= feq[0]; t[1] *= feq[1]; t[2] *= feq[2]; t[3] *= feq[3];
        o_acc[nt] = t;
      }
    }

    // per-nt group: exp, sum, pack -> LDS (caps live pv regs at 4)
    float rs = 0.f;
    #pragma unroll
    for (int nt = 0; nt < 4; nt++){
      float p0 = exp2f(sc[nt * 4 + 0] - m_c);
      float p1 = exp2f(sc[nt * 4 + 1] - m_c);
      float p2 = exp2f(sc[nt * 4 + 2] - m_c);
      float p3 = exp2f(sc[nt * 4 + 3] - m_c);
      rs += (p0 + p1) + (p2 + p3);
      uint2 pk;
      pk.x = cvt_pk_bf16(p0, p1);
      pk.y = cvt_pk_bf16(p2, p3);
      *(uint2*)&Pw[c * 64 + ((nt * 16 + g * 4) ^ swr)] = pk;
    }
    rs += __shfl_xor(rs, 16);
    rs += __shfl_xor(rs, 32);
    l_c += rs;

    // O += P V
    #pragma unroll
    for (int ks = 0; ks < 2; ks++){
      s16x8 pa = *(const s16x8*)&Pw[c * 64 + ((ks * 32 + g * 8) ^ swr)];
      #pragma unroll
      for (int nt = 0; nt < 4; nt++)
        o_acc[nt] = __builtin_amdgcn_mfma_f32_16x16x32_bf16(pa, vC[nt * 2 + ks], o_acc[nt], 0, 0, 0);
    }
  };

  // ---- software-pipelined main loop (ping-pong kA/kB) ----
  int t = wave;
  if (t < nkt) loadK(kA, t);
  while (t < nkt){
    loadV(t);                            // issue V(t) first (oldest after kA)
    int tn = t + 4;
    if (tn < nkt) loadK(kB, tn);         // prefetch next K, stays in flight across compute
    __builtin_amdgcn_sched_barrier(0);   // pin: loads may not sink past here
    computeT(kA, t);
    t = tn;
    if (t >= nkt) break;
    loadV(t);
    tn = t + 4;
    if (tn < nkt) loadK(kA, tn);
    __builtin_amdgcn_sched_barrier(0);
    computeT(kB, t);
    t = tn;
  }

  // ---- split-K merge ----
  if (wave > 0){
    int w = wave - 1;
    #pragma unroll
    for (int nt = 0; nt < 4; nt++){
      *(float2*)&Mo[w][lane][nt * 4]     = (float2){o_acc[nt][0], o_acc[nt][1]};
      *(float2*)&Mo[w][lane][nt * 4 + 2] = (float2){o_acc[nt][2], o_acc[nt][3]};
    }
    if (lane < 16){ Ml[w][c] = m_c; Ll[w][c] = l_c; }
  }
  __syncthreads();
  if (wave == 0){
    if (lane < 16){
      float mw0 = Ml[0][c], mw1 = Ml[1][c], mw2 = Ml[2][c];
      float m_tot = fmaxf(fmaxf(m_c, mw0), fmaxf(mw1, mw2));
      float f0 = exp2f(m_c - m_tot);
      float fa = exp2f(mw0 - m_tot);
      float fb = exp2f(mw1 - m_tot);
      float fc = exp2f(mw2 - m_tot);
      float l_tot = l_c * f0 + Ll[0][c] * fa + Ll[1][c] * fb + Ll[2][c] * fc;
      Fq[0][c] = f0; Fq[1][c] = fa; Fq[2][c] = fb; Fq[3][c] = fc;
      Linv[c] = 1.0f / l_tot;
    }
    asm volatile("s_waitcnt lgkmcnt(0)" ::: "memory");

    const int h = bh & 15, b = bh >> 4;
    #pragma unroll
    for (int r = 0; r < 4; r++){
      int row = g * 4 + r;
      float f0 = Fq[0][row], fa = Fq[1][row], fb = Fq[2][row], fcq = Fq[3][row];
      float li = Linv[row];
      int q = q0 + row;
      #pragma unroll
      for (int nt = 0; nt < 4; nt++){
        float v = o_acc[nt][r] * f0
                + Mo[0][lane][nt * 4 + r] * fa
                + Mo[1][lane][nt * 4 + r] * fb
                + Mo[2][lane][nt * 4 + r] * fcq;
        Og[(size_t)(b * S_ + q) * D_ + h * HS_ + nt * 16 + c] = f2bf(v * li);
      }
    }
  }
}

extern "C" void kernel_launch(void* const* d_in, const int* in_sizes, int n_in,
                              void* d_out, int out_size, void* d_ws, size_t ws_size,
                              hipStream_t stream)
{
  const float* x    = (const float*)d_in[0];
  const float* Wqkv = (const float*)d_in[1];
  const float* bqkv = (const float*)d_in[2];
  const float* Wout = (const float*)d_in[3];
  const float* bout = (const float*)d_in[4];

  char* ws = (char*)d_ws;
  short* xb     = (short*)(ws);                 //  8 MB [4096][1024] bf16 (reused as O_tok)
  short* Wqkv_t = (short*)(ws + 8388608);       //  6 MB [3072][1024]
  short* Wout_t = (short*)(ws + 14680064);      //  2 MB [1024][1024]
  short* Qg     = (short*)(ws + 16777216);      //  8 MB [32][2048][64]
  short* Kg     = Qg + 4194304;                 //  8 MB
  short* Vg     = Qg + 8388608;                 //  8 MB
  short* Vt     = (short*)(ws + 41943040);      //  8 MB [32][64][2048]
  short* Otok   = xb;                           //  reuse (xb dead after QKV GEMM)

  k_cvt<<<4096, 256, 0, stream>>>(x, xb, TOK * D_ / 4);
  k_tconv<<<dim3(96, 32), 256, 0, stream>>>(Wqkv, Wqkv_t, 1024, 3072);
  k_tconv<<<dim3(32, 32), 256, 0, stream>>>(Wout, Wout_t, 1024, 1024);
  k_gemm<0><<<dim3(32, 24), 256, 0, stream>>>(xb, Wqkv_t, bqkv, (void*)Qg);
  k_vtrans<<<dim3(32, 32), 256, 0, stream>>>(Vg, Vt);
  k_attn<<<dim3(4096), 256, 0, stream>>>(Qg, Kg, Vt, Otok);
  k_gemm<1><<<dim3(32, 8), 256, 0, stream>>>(Otok, Wout_t, bout, d_out);
}

// Round 6
// 222.200 us; speedup vs baseline: 1.2982x; 1.2982x over previous
//
#include <hip/hip_runtime.h>
#include <hip/hip_bf16.h>
#include <stdint.h>

typedef __attribute__((ext_vector_type(4))) float f32x4;
typedef __attribute__((ext_vector_type(8))) short s16x8;
typedef __attribute__((ext_vector_type(4))) short s16x4;

#define B_   2
#define S_   2048
#define D_   1024
#define H_   16
#define HS_  64
#define TOK  (B_*S_)   // 4096
#define BH_  (B_*H_)   // 32

__device__ __forceinline__ short f2bf(float f){
  union { float f; uint32_t u; } v; v.f = f;
  uint32_t u = v.u;
  u += 0x7fffu + ((u >> 16) & 1u);   // round-to-nearest-even
  return (short)(u >> 16);
}

__device__ __forceinline__ uint32_t cvt_pk_bf16(float lo, float hi){
  uint32_t r;
  asm("v_cvt_pk_bf16_f32 %0, %1, %2" : "=v"(r) : "v"(lo), "v"(hi));
  return r;
}

__device__ __forceinline__ void gload_lds16(const void* g, void* l){
  __builtin_amdgcn_global_load_lds((const __attribute__((address_space(1))) void*)g,
                                   (__attribute__((address_space(3))) void*)l, 16, 0, 0);
}

// ---------------- fp32 -> bf16 convert (vectorized) ----------------
__global__ void k_cvt(const float* __restrict__ src, short* __restrict__ dst, int n4){
  int i = blockIdx.x * blockDim.x + threadIdx.x;
  if (i < n4){
    float4 v = reinterpret_cast<const float4*>(src)[i];
    s16x4 o;
    o.x = f2bf(v.x); o.y = f2bf(v.y); o.z = f2bf(v.z); o.w = f2bf(v.w);
    reinterpret_cast<s16x4*>(dst)[i] = o;
  }
}

// ---------------- transpose + convert: src[K][N] f32 -> dst[N][K] bf16 ----------------
__global__ void k_tconv(const float* __restrict__ src, short* __restrict__ dst, int K, int N){
  __shared__ short tile[32][33];
  const int n0 = blockIdx.x * 32, k0 = blockIdx.y * 32;
  const int c = threadIdx.x & 31, r8 = threadIdx.x >> 5;
  #pragma unroll
  for (int j = 0; j < 4; j++){
    int k = r8 + j * 8;
    tile[c][k] = f2bf(src[(size_t)(k0 + k) * N + n0 + c]);
  }
  __syncthreads();
  #pragma unroll
  for (int j = 0; j < 4; j++){
    int nl = r8 + j * 8;
    dst[(size_t)(n0 + nl) * K + k0 + c] = tile[nl][c];
  }
}

// ---------------- bf16 GEMM, 128x128 tile, BK=32, K=1024 fixed ----------------
template<int EPI>
__global__ __launch_bounds__(256, 2) void k_gemm(
    const short* __restrict__ A, const short* __restrict__ Bt,
    const float* __restrict__ bias, void* __restrict__ outp)
{
  __shared__ short Al[128 * 32];
  __shared__ short Bl[128 * 32];
  const int tid = threadIdx.x;
  const int lane = tid & 63, wave = tid >> 6;
  const int m0 = blockIdx.x * 128, n0 = blockIdx.y * 128;
  const int wm = (wave >> 1) * 64, wn = (wave & 1) * 64;
  const int c = lane & 15, g = lane >> 4;

  f32x4 acc[4][4];
  #pragma unroll
  for (int i = 0; i < 4; i++)
    #pragma unroll
    for (int j = 0; j < 4; j++) acc[i][j] = (f32x4){0.f, 0.f, 0.f, 0.f};

  const short* Asrc = A + (size_t)m0 * 1024;
  const short* Bsrc = Bt + (size_t)n0 * 1024;

  for (int kt = 0; kt < 1024; kt += 32){
    __syncthreads();
    #pragma unroll
    for (int j = 0; j < 2; j++){
      int gc = (wave * 2 + j) * 64 + lane;
      int row = gc >> 2, c8 = gc & 3;
      gload_lds16(Asrc + (size_t)row * 1024 + kt + c8 * 8, Al + (size_t)(wave * 2 + j) * 512);
      gload_lds16(Bsrc + (size_t)row * 1024 + kt + c8 * 8, Bl + (size_t)(wave * 2 + j) * 512);
    }
    __syncthreads();

    s16x8 af[4], bq[4];
    #pragma unroll
    for (int t = 0; t < 4; t++){
      af[t] = *(const s16x8*)&Al[(wm + t * 16 + c) * 32 + g * 8];
      bq[t] = *(const s16x8*)&Bl[(wn + t * 16 + c) * 32 + g * 8];
    }
    #pragma unroll
    for (int mt = 0; mt < 4; mt++)
      #pragma unroll
      for (int nt = 0; nt < 4; nt++)
        acc[mt][nt] = __builtin_amdgcn_mfma_f32_16x16x32_bf16(af[mt], bq[nt], acc[mt][nt], 0, 0, 0);
  }

  if (EPI == 0){
    short* Qb = (short*)outp;
    const size_t QSZ = (size_t)BH_ * S_ * HS_;
    #pragma unroll
    for (int mt = 0; mt < 4; mt++){
      #pragma unroll
      for (int nt = 0; nt < 4; nt++){
        int n = n0 + wn + nt * 16 + c;
        float bv = bias[n];
        int sel = n >> 10, hn = (n >> 6) & 15, d = n & 63;
        #pragma unroll
        for (int r = 0; r < 4; r++){
          int token = m0 + wm + mt * 16 + g * 4 + r;
          int b = token >> 11, s = token & 2047;
          float v = acc[mt][nt][r] + bv;
          Qb[(size_t)sel * QSZ + ((size_t)(b * H_ + hn) * S_ + s) * HS_ + d] = f2bf(v);
        }
      }
    }
  } else {
    float* O = (float*)outp;
    #pragma unroll
    for (int mt = 0; mt < 4; mt++){
      #pragma unroll
      for (int nt = 0; nt < 4; nt++){
        int n = n0 + wn + nt * 16 + c;
        float bv = bias[n];
        #pragma unroll
        for (int r = 0; r < 4; r++){
          int token = m0 + wm + mt * 16 + g * 4 + r;
          O[(size_t)token * 1024 + n] = acc[mt][nt][r] + bv;
        }
      }
    }
  }
}

// ---------------- V [bh][s][64] -> Vt [bh][64][s] (bf16) ----------------
__global__ void k_vtrans(const short* __restrict__ Vg, short* __restrict__ Vt){
  __shared__ short t[64 * 80];
  const int bh = blockIdx.y;
  const int s0 = blockIdx.x * 64;
  const int tid = threadIdx.x;
  const int r = tid >> 3, c8 = (tid & 7) * 8;
  #pragma unroll
  for (int p = 0; p < 2; p++){
    int ss = r + p * 32;
    s16x8 v = *(const s16x8*)&Vg[((size_t)bh * S_ + s0 + ss) * HS_ + c8];
    #pragma unroll
    for (int i = 0; i < 8; i++) t[(c8 + i) * 80 + ss] = v[i];
  }
  __syncthreads();
  #pragma unroll
  for (int p = 0; p < 2; p++){
    int d = r + p * 32;
    s16x8 v = *(const s16x8*)&t[d * 80 + c8];
    *(s16x8*)&Vt[((size_t)bh * HS_ + d) * S_ + s0 + c8] = v;
  }
}

// ---------------- causal flash attention: 128-q block, LDS-staged K/V ----------------
// Block = 4 waves x 32 q-rows (no split-K). K/V 64-key tiles staged to double-
// buffered LDS via global_load_lds (zero VGPR for in-flight data; round-5 spill
// fix). Swizzle: linear LDS dest + inverse-swizzled GLOBAL source + swizzled
// ds_read (both-sides rule). 2-phase: stage(next) || compute(cur); 1 barrier/iter.
__global__ __launch_bounds__(256, 3) void k_attn(
    const short* __restrict__ Qg, const short* __restrict__ Kg,
    const short* __restrict__ Vt, short* __restrict__ Og)
{
  __shared__ short Kl[2][64 * 64];   // [buf][row=key][chunk] chunk swizzled ^(row&7)
  __shared__ short Vl[2][64 * 64];   // [buf][row=d][chunk]  (from Vt, same swizzle)
  __shared__ short Pl[4][32 * 64];   // per-wave P [row=q][chunk], same swizzle

  const int tid = threadIdx.x, lane = tid & 63, wave = tid >> 6;
  const int c = lane & 15, g = lane >> 4;
  const int c7 = c & 7;

  // block -> (qt desc, bh). 512 blocks; 32 ≡ 0 mod 8 so bh%8 = XCD affinity.
  const int p = blockIdx.x;
  const int qt = 15 - (p >> 5);            // 0..15, longest first
  const int bh = p & 31;
  const int q0 = qt * 128;
  const int q0w = q0 + wave * 32;          // this wave's 32 q-rows
  const int nkt = 2 * qt + 2;              // 64-key tiles for the whole block
  const size_t basebh = (size_t)bh * S_ * HS_;
  const short* Kb  = Kg + basebh;
  const short* Vtb = Vt + (size_t)bh * HS_ * S_;

  // Q fragments: qb[rt][h] = Q[q0w + rt*16 + c][h*32 + g*8 ..+7]
  s16x8 qb[2][2];
  #pragma unroll
  for (int rt = 0; rt < 2; rt++)
    #pragma unroll
    for (int h = 0; h < 2; h++)
      qb[rt][h] = *(const s16x8*)&Qg[basebh + (size_t)(q0w + rt * 16 + c) * HS_ + h * 32 + g * 8];

  f32x4 o_acc[2][4];
  #pragma unroll
  for (int rt = 0; rt < 2; rt++)
    #pragma unroll
    for (int nt = 0; nt < 4; nt++) o_acc[rt][nt] = (f32x4){0.f, 0.f, 0.f, 0.f};
  float m_[2] = {-3e38f, -3e38f}, l_[2] = {0.f, 0.f};

  short* Pw = &Pl[wave][0];
  const float SC = 0.125f * 1.44269504f;   // scale * log2(e)

  // staging constants: thread covers rows {srow, srow+32}, chunk schk; the global
  // source column is pre-swizzled so a linear LDS write yields swizzled layout.
  const int srow = tid >> 3;               // 0..31
  const int schk = tid & 7;
  const int swc  = ((schk ^ (srow & 7)) * 8);  // pre-swizzled col (elems)
  const int ldsoff0 = wave * 512;              // shorts; +2048 for i=1

  auto STAGE = [&](int buf, int kt){
    const int k0 = kt * 64;
    #pragma unroll
    for (int i = 0; i < 2; i++){
      gload_lds16(Kb + (size_t)(k0 + srow + 32 * i) * HS_ + swc, &Kl[buf][i * 2048 + ldsoff0]);
      gload_lds16(Vtb + (size_t)(srow + 32 * i) * S_ + k0 + swc, &Vl[buf][i * 2048 + ldsoff0]);
    }
  };

  auto COMPUTE = [&](int buf, int kt){
    const int k0 = kt * 64;
    const short* KB = &Kl[buf][0];
    const short* VB = &Vl[buf][0];

    // K fragments from LDS (swizzled read), shared across both rt groups
    s16x8 ka[4][2];
    #pragma unroll
    for (int kf = 0; kf < 4; kf++)
      #pragma unroll
      for (int h = 0; h < 2; h++)
        ka[kf][h] = *(const s16x8*)&KB[(kf * 16 + c) * 64 + ((h * 4 + g) ^ c7) * 8];

    #pragma unroll
    for (int rt = 0; rt < 2; rt++){
      const int qlo = q0w + rt * 16;
      if (k0 > qlo + 15) continue;         // fully masked for this row group

      // S^T: st[kf][r] = S[qlo + c][k0 + kf*16 + g*4 + r]
      f32x4 st[4];
      #pragma unroll
      for (int kf = 0; kf < 4; kf++){
        f32x4 a = (f32x4){0.f, 0.f, 0.f, 0.f};
        a = __builtin_amdgcn_mfma_f32_16x16x32_bf16(ka[kf][0], qb[rt][0], a, 0, 0, 0);
        a = __builtin_amdgcn_mfma_f32_16x16x32_bf16(ka[kf][1], qb[rt][1], a, 0, 0, 0);
        st[kf] = a;
      }

      const bool edge = (k0 + 63 > qlo);
      float sc[16];
      float tmax = -3e38f;
      #pragma unroll
      for (int kf = 0; kf < 4; kf++)
        #pragma unroll
        for (int r = 0; r < 4; r++){
          float v = st[kf][r] * SC;
          if (edge && (k0 + kf * 16 + g * 4 + r > qlo + c)) v = -3e38f;
          sc[kf * 4 + r] = v;
          tmax = fmaxf(tmax, v);
        }
      tmax = fmaxf(tmax, __shfl_xor(tmax, 16));
      tmax = fmaxf(tmax, __shfl_xor(tmax, 32));

      // T13: skip rescale when the running max doesn't grow
      if (!__all(tmax <= m_[rt])){
        float mnew = fmaxf(m_[rt], tmax);
        float fe = exp2f(m_[rt] - mnew);
        m_[rt] = mnew;
        l_[rt] *= fe;
        float feq0 = __shfl(fe, g * 4 + 0), feq1 = __shfl(fe, g * 4 + 1);
        float feq2 = __shfl(fe, g * 4 + 2), feq3 = __shfl(fe, g * 4 + 3);
        #pragma unroll
        for (int nt = 0; nt < 4; nt++){
          f32x4 t = o_acc[rt][nt];
          t[0] *= feq0; t[1] *= feq1; t[2] *= feq2; t[3] *= feq3;
          o_acc[rt][nt] = t;
        }
      }

      // exp + pack P -> per-wave LDS (swizzled), accumulate row-sum
      float rs = 0.f;
      const int prow = rt * 16 + c;
      #pragma unroll
      for (int kf = 0; kf < 4; kf++){
        float p0 = exp2f(sc[kf * 4 + 0] - m_[rt]);
        float p1 = exp2f(sc[kf * 4 + 1] - m_[rt]);
        float p2 = exp2f(sc[kf * 4 + 2] - m_[rt]);
        float p3 = exp2f(sc[kf * 4 + 3] - m_[rt]);
        rs += (p0 + p1) + (p2 + p3);
        uint2 pk;
        pk.x = cvt_pk_bf16(p0, p1);
        pk.y = cvt_pk_bf16(p2, p3);
        // keys kf*16 + g*4 ..+3 live in chunk (2kf + (g>>1)), half (g&1)
        *(uint2*)&Pw[prow * 64 + ((2 * kf + (g >> 1)) ^ c7) * 8 + (g & 1) * 4] = pk;
      }
      rs += __shfl_xor(rs, 16);
      rs += __shfl_xor(rs, 32);
      l_[rt] += rs;
    }

    // PV: vb from staged Vt tile, pa from per-wave P
    s16x8 vb[4][2];
    #pragma unroll
    for (int nt = 0; nt < 4; nt++)
      #pragma unroll
      for (int ks = 0; ks < 2; ks++)
        vb[nt][ks] = *(const s16x8*)&VB[(nt * 16 + c) * 64 + ((ks * 4 + g) ^ c7) * 8];

    #pragma unroll
    for (int rt = 0; rt < 2; rt++){
      if (k0 > q0w + rt * 16 + 15) continue;
      #pragma unroll
      for (int ks = 0; ks < 2; ks++){
        s16x8 pa = *(const s16x8*)&Pw[(rt * 16 + c) * 64 + ((ks * 4 + g) ^ c7) * 8];
        #pragma unroll
        for (int nt = 0; nt < 4; nt++)
          o_acc[rt][nt] = __builtin_amdgcn_mfma_f32_16x16x32_bf16(pa, vb[nt][ks], o_acc[rt][nt], 0, 0, 0);
      }
    }
  };

  // ---- 2-phase main loop: stage(next) || compute(cur) ----
  STAGE(0, 0);
  __syncthreads();                         // drains vmcnt(0): buf0 ready
  int cur = 0;
  for (int t = 0; t < nkt; t++){
    if (t + 1 < nkt) STAGE(cur ^ 1, t + 1);
    COMPUTE(cur, t);
    __syncthreads();                       // vmcnt+lgkm drain + barrier
    cur ^= 1;
  }

  // ---- epilogue: O / l -> [token][1024] bf16 ----
  const int h = bh & 15, b = bh >> 4;
  #pragma unroll
  for (int rt = 0; rt < 2; rt++){
    float linv = 1.0f / l_[rt];
    float lr0 = __shfl(linv, g * 4 + 0), lr1 = __shfl(linv, g * 4 + 1);
    float lr2 = __shfl(linv, g * 4 + 2), lr3 = __shfl(linv, g * 4 + 3);
    #pragma unroll
    for (int nt = 0; nt < 4; nt++){
      int q = q0w + rt * 16 + g * 4;
      size_t base = (size_t)(b * S_ + q) * D_ + h * HS_ + nt * 16 + c;
      Og[base]            = f2bf(o_acc[rt][nt][0] * lr0);
      Og[base + D_]       = f2bf(o_acc[rt][nt][1] * lr1);
      Og[base + 2 * D_]   = f2bf(o_acc[rt][nt][2] * lr2);
      Og[base + 3 * D_]   = f2bf(o_acc[rt][nt][3] * lr3);
    }
  }
}

extern "C" void kernel_launch(void* const* d_in, const int* in_sizes, int n_in,
                              void* d_out, int out_size, void* d_ws, size_t ws_size,
                              hipStream_t stream)
{
  const float* x    = (const float*)d_in[0];
  const float* Wqkv = (const float*)d_in[1];
  const float* bqkv = (const float*)d_in[2];
  const float* Wout = (const float*)d_in[3];
  const float* bout = (const float*)d_in[4];

  char* ws = (char*)d_ws;
  short* xb     = (short*)(ws);                 //  8 MB [4096][1024] bf16 (reused as O_tok)
  short* Wqkv_t = (short*)(ws + 8388608);       //  6 MB [3072][1024]
  short* Wout_t = (short*)(ws + 14680064);      //  2 MB [1024][1024]
  short* Qg     = (short*)(ws + 16777216);      //  8 MB [32][2048][64]
  short* Kg     = Qg + 4194304;                 //  8 MB
  short* Vg     = Qg + 8388608;                 //  8 MB
  short* Vt     = (short*)(ws + 41943040);      //  8 MB [32][64][2048]
  short* Otok   = xb;                           //  reuse (xb dead after QKV GEMM)

  k_cvt<<<4096, 256, 0, stream>>>(x, xb, TOK * D_ / 4);
  k_tconv<<<dim3(96, 32), 256, 0, stream>>>(Wqkv, Wqkv_t, 1024, 3072);
  k_tconv<<<dim3(32, 32), 256, 0, stream>>>(Wout, Wout_t, 1024, 1024);
  k_gemm<0><<<dim3(32, 24), 256, 0, stream>>>(xb, Wqkv_t, bqkv, (void*)Qg);
  k_vtrans<<<dim3(32, 32), 256, 0, stream>>>(Vg, Vt);
  k_attn<<<dim3(512), 256, 0, stream>>>(Qg, Kg, Vt, Otok);
  k_gemm<1><<<dim3(32, 8), 256, 0, stream>>>(Otok, Wout_t, bout, d_out);
}

// Round 8
// 221.859 us; speedup vs baseline: 1.3002x; 1.0015x over previous
//
#include <hip/hip_runtime.h>
#include <hip/hip_bf16.h>
#include <stdint.h>

typedef __attribute__((ext_vector_type(4))) float f32x4;
typedef __attribute__((ext_vector_type(8))) short s16x8;
typedef __attribute__((ext_vector_type(4))) short s16x4;

#define B_   2
#define S_   2048
#define D_   1024
#define H_   16
#define HS_  64
#define TOK  (B_*S_)   // 4096
#define BH_  (B_*H_)   // 32

__device__ __forceinline__ short f2bf(float f){
  union { float f; uint32_t u; } v; v.f = f;
  uint32_t u = v.u;
  u += 0x7fffu + ((u >> 16) & 1u);   // round-to-nearest-even
  return (short)(u >> 16);
}

__device__ __forceinline__ uint32_t cvt_pk_bf16(float lo, float hi){
  uint32_t r;
  asm("v_cvt_pk_bf16_f32 %0, %1, %2" : "=v"(r) : "v"(lo), "v"(hi));
  return r;
}

__device__ __forceinline__ void gload_lds16(const void* g, void* l){
  __builtin_amdgcn_global_load_lds((const __attribute__((address_space(1))) void*)g,
                                   (__attribute__((address_space(3))) void*)l, 16, 0, 0);
}

// ---------------- fp32 -> bf16 convert (vectorized) ----------------
__global__ void k_cvt(const float* __restrict__ src, short* __restrict__ dst, int n4){
  int i = blockIdx.x * blockDim.x + threadIdx.x;
  if (i < n4){
    float4 v = reinterpret_cast<const float4*>(src)[i];
    s16x4 o;
    o.x = f2bf(v.x); o.y = f2bf(v.y); o.z = f2bf(v.z); o.w = f2bf(v.w);
    reinterpret_cast<s16x4*>(dst)[i] = o;
  }
}

// ---------------- transpose + convert: src[K][N] f32 -> dst[N][K] bf16 ----------------
__global__ void k_tconv(const float* __restrict__ src, short* __restrict__ dst, int K, int N){
  __shared__ short tile[32][33];
  const int n0 = blockIdx.x * 32, k0 = blockIdx.y * 32;
  const int c = threadIdx.x & 31, r8 = threadIdx.x >> 5;
  #pragma unroll
  for (int j = 0; j < 4; j++){
    int k = r8 + j * 8;
    tile[c][k] = f2bf(src[(size_t)(k0 + k) * N + n0 + c]);
  }
  __syncthreads();
  #pragma unroll
  for (int j = 0; j < 4; j++){
    int nl = r8 + j * 8;
    dst[(size_t)(n0 + nl) * K + k0 + c] = tile[nl][c];
  }
}

// ---------------- bf16 GEMM, 128x128 tile, BK=32, K=1024 (QKV: EPI scatter) ----------------
__global__ __launch_bounds__(256, 2) void k_gemm_qkv(
    const short* __restrict__ A, const short* __restrict__ Bt,
    const float* __restrict__ bias, short* __restrict__ Qb)
{
  __shared__ short Al[128 * 32];
  __shared__ short Bl[128 * 32];
  const int tid = threadIdx.x;
  const int lane = tid & 63, wave = tid >> 6;
  const int m0 = blockIdx.x * 128, n0 = blockIdx.y * 128;
  const int wm = (wave >> 1) * 64, wn = (wave & 1) * 64;
  const int c = lane & 15, g = lane >> 4;

  f32x4 acc[4][4];
  #pragma unroll
  for (int i = 0; i < 4; i++)
    #pragma unroll
    for (int j = 0; j < 4; j++) acc[i][j] = (f32x4){0.f, 0.f, 0.f, 0.f};

  const short* Asrc = A + (size_t)m0 * 1024;
  const short* Bsrc = Bt + (size_t)n0 * 1024;

  for (int kt = 0; kt < 1024; kt += 32){
    __syncthreads();
    #pragma unroll
    for (int j = 0; j < 2; j++){
      int gc = (wave * 2 + j) * 64 + lane;
      int row = gc >> 2, c8 = gc & 3;
      gload_lds16(Asrc + (size_t)row * 1024 + kt + c8 * 8, Al + (size_t)(wave * 2 + j) * 512);
      gload_lds16(Bsrc + (size_t)row * 1024 + kt + c8 * 8, Bl + (size_t)(wave * 2 + j) * 512);
    }
    __syncthreads();

    s16x8 af[4], bq[4];
    #pragma unroll
    for (int t = 0; t < 4; t++){
      af[t] = *(const s16x8*)&Al[(wm + t * 16 + c) * 32 + g * 8];
      bq[t] = *(const s16x8*)&Bl[(wn + t * 16 + c) * 32 + g * 8];
    }
    #pragma unroll
    for (int mt = 0; mt < 4; mt++)
      #pragma unroll
      for (int nt = 0; nt < 4; nt++)
        acc[mt][nt] = __builtin_amdgcn_mfma_f32_16x16x32_bf16(af[mt], bq[nt], acc[mt][nt], 0, 0, 0);
  }

  const size_t QSZ = (size_t)BH_ * S_ * HS_;
  #pragma unroll
  for (int mt = 0; mt < 4; mt++){
    #pragma unroll
    for (int nt = 0; nt < 4; nt++){
      int n = n0 + wn + nt * 16 + c;
      float bv = bias[n];
      int sel = n >> 10, hn = (n >> 6) & 15, d = n & 63;
      #pragma unroll
      for (int r = 0; r < 4; r++){
        int token = m0 + wm + mt * 16 + g * 4 + r;
        int b = token >> 11, s = token & 2047;
        float v = acc[mt][nt][r] + bv;
        Qb[(size_t)sel * QSZ + ((size_t)(b * H_ + hn) * S_ + s) * HS_ + d] = f2bf(v);
      }
    }
  }
}

// ---------------- out-proj GEMM, 64x128 tile (512 blocks = 2/CU; was 1/CU) ----------------
__global__ __launch_bounds__(256, 2) void k_gemm_o(
    const short* __restrict__ A, const short* __restrict__ Bt,
    const float* __restrict__ bias, float* __restrict__ O)
{
  __shared__ short Al[64 * 32];
  __shared__ short Bl[128 * 32];
  const int tid = threadIdx.x;
  const int lane = tid & 63, wave = tid >> 6;
  const int m0 = blockIdx.x * 64, n0 = blockIdx.y * 128;
  const int wn = wave * 32;
  const int c = lane & 15, g = lane >> 4;

  f32x4 acc[4][2];
  #pragma unroll
  for (int i = 0; i < 4; i++)
    #pragma unroll
    for (int j = 0; j < 2; j++) acc[i][j] = (f32x4){0.f, 0.f, 0.f, 0.f};

  const short* Asrc = A + (size_t)m0 * 1024;
  const short* Bsrc = Bt + (size_t)n0 * 1024;

  for (int kt = 0; kt < 1024; kt += 32){
    __syncthreads();
    {
      int gc = wave * 64 + lane;           // A: 256 chunks of 16B
      int row = gc >> 2, c8 = gc & 3;
      gload_lds16(Asrc + (size_t)row * 1024 + kt + c8 * 8, Al + (size_t)wave * 512);
    }
    #pragma unroll
    for (int j = 0; j < 2; j++){           // B: 512 chunks
      int gc = (wave * 2 + j) * 64 + lane;
      int row = gc >> 2, c8 = gc & 3;
      gload_lds16(Bsrc + (size_t)row * 1024 + kt + c8 * 8, Bl + (size_t)(wave * 2 + j) * 512);
    }
    __syncthreads();

    s16x8 af[4], bq[2];
    #pragma unroll
    for (int t = 0; t < 4; t++)
      af[t] = *(const s16x8*)&Al[(t * 16 + c) * 32 + g * 8];
    #pragma unroll
    for (int n = 0; n < 2; n++)
      bq[n] = *(const s16x8*)&Bl[(wn + n * 16 + c) * 32 + g * 8];
    #pragma unroll
    for (int mt = 0; mt < 4; mt++)
      #pragma unroll
      for (int n = 0; n < 2; n++)
        acc[mt][n] = __builtin_amdgcn_mfma_f32_16x16x32_bf16(af[mt], bq[n], acc[mt][n], 0, 0, 0);
  }

  #pragma unroll
  for (int mt = 0; mt < 4; mt++){
    #pragma unroll
    for (int n = 0; n < 2; n++){
      int nn = n0 + wn + n * 16 + c;
      float bv = bias[nn];
      #pragma unroll
      for (int r = 0; r < 4; r++){
        int token = m0 + mt * 16 + g * 4 + r;
        O[(size_t)token * 1024 + nn] = acc[mt][n][r] + bv;
      }
    }
  }
}

// ---------------- V [bh][s][64] -> Vt [bh][64][s] (bf16) ----------------
__global__ void k_vtrans(const short* __restrict__ Vg, short* __restrict__ Vt){
  __shared__ short t[64 * 80];
  const int bh = blockIdx.y;
  const int s0 = blockIdx.x * 64;
  const int tid = threadIdx.x;
  const int r = tid >> 3, c8 = (tid & 7) * 8;
  #pragma unroll
  for (int p = 0; p < 2; p++){
    int ss = r + p * 32;
    s16x8 v = *(const s16x8*)&Vg[((size_t)bh * S_ + s0 + ss) * HS_ + c8];
    #pragma unroll
    for (int i = 0; i < 8; i++) t[(c8 + i) * 80 + ss] = v[i];
  }
  __syncthreads();
  #pragma unroll
  for (int p = 0; p < 2; p++){
    int d = r + p * 32;
    s16x8 v = *(const s16x8*)&t[d * 80 + c8];
    *(s16x8*)&Vt[((size_t)bh * HS_ + d) * S_ + s0 + c8] = v;
  }
}

// ---------------- causal flash attention: 128-q block, LDS-staged K/V ----------------
// Pairing: block p<256 gets qt=15-(p>>5), p>=256 gets qt=(p-256)>>5. Blocks p and
// p+256 co-locate on one CU (same XCD since 256%8==0) and their work sums to a
// constant 34 tile-iters -> flat CU load (round-6 imbalance fix).
__global__ __launch_bounds__(256, 3) void k_attn(
    const short* __restrict__ Qg, const short* __restrict__ Kg,
    const short* __restrict__ Vt, short* __restrict__ Og)
{
  __shared__ short Kl[2][64 * 64];   // [buf][row=key][chunk] chunk swizzled ^(row&7)
  __shared__ short Vl[2][64 * 64];   // [buf][row=d][chunk]  (from Vt, same swizzle)
  __shared__ short Pl[4][32 * 64];   // per-wave P [row=q][chunk], same swizzle

  const int tid = threadIdx.x, lane = tid & 63, wave = tid >> 6;
  const int c = lane & 15, g = lane >> 4;
  const int c7 = c & 7;

  const int p = blockIdx.x;
  const int qt = (p < 256) ? (15 - (p >> 5)) : ((p - 256) >> 5);
  const int bh = p & 31;
  const int q0 = qt * 128;
  const int q0w = q0 + wave * 32;          // this wave's 32 q-rows
  const int nkt = 2 * qt + 2;              // 64-key tiles for the whole block
  const size_t basebh = (size_t)bh * S_ * HS_;
  const short* Kb  = Kg + basebh;
  const short* Vtb = Vt + (size_t)bh * HS_ * S_;

  // Q fragments: qb[rt][h] = Q[q0w + rt*16 + c][h*32 + g*8 ..+7]
  s16x8 qb[2][2];
  #pragma unroll
  for (int rt = 0; rt < 2; rt++)
    #pragma unroll
    for (int h = 0; h < 2; h++)
      qb[rt][h] = *(const s16x8*)&Qg[basebh + (size_t)(q0w + rt * 16 + c) * HS_ + h * 32 + g * 8];

  f32x4 o_acc[2][4];
  #pragma unroll
  for (int rt = 0; rt < 2; rt++)
    #pragma unroll
    for (int nt = 0; nt < 4; nt++) o_acc[rt][nt] = (f32x4){0.f, 0.f, 0.f, 0.f};
  float m_[2] = {-3e38f, -3e38f}, l_[2] = {0.f, 0.f};   // m in RAW S units

  short* Pw = &Pl[wave][0];
  const float SC = 0.125f * 1.44269504f;   // scale * log2(e)

  const int srow = tid >> 3;               // staging: rows {srow, srow+32}
  const int schk = tid & 7;
  const int swc  = ((schk ^ (srow & 7)) * 8);  // pre-swizzled source col (elems)
  const int ldsoff0 = wave * 512;

  auto STAGE = [&](int buf, int kt){
    const int k0 = kt * 64;
    #pragma unroll
    for (int i = 0; i < 2; i++){
      gload_lds16(Kb + (size_t)(k0 + srow + 32 * i) * HS_ + swc, &Kl[buf][i * 2048 + ldsoff0]);
      gload_lds16(Vtb + (size_t)(srow + 32 * i) * S_ + k0 + swc, &Vl[buf][i * 2048 + ldsoff0]);
    }
  };

  auto COMPUTE = [&](int buf, int kt){
    const int k0 = kt * 64;
    const short* KB = &Kl[buf][0];
    const short* VB = &Vl[buf][0];

    s16x8 ka[4][2];
    #pragma unroll
    for (int kf = 0; kf < 4; kf++)
      #pragma unroll
      for (int h = 0; h < 2; h++)
        ka[kf][h] = *(const s16x8*)&KB[(kf * 16 + c) * 64 + ((h * 4 + g) ^ c7) * 8];

    #pragma unroll
    for (int rt = 0; rt < 2; rt++){
      const int qlo = q0w + rt * 16;
      if (k0 > qlo + 15) continue;         // fully masked for this row group

      f32x4 st[4];
      #pragma unroll
      for (int kf = 0; kf < 4; kf++){
        f32x4 a = (f32x4){0.f, 0.f, 0.f, 0.f};
        a = __builtin_amdgcn_mfma_f32_16x16x32_bf16(ka[kf][0], qb[rt][0], a, 0, 0, 0);
        a = __builtin_amdgcn_mfma_f32_16x16x32_bf16(ka[kf][1], qb[rt][1], a, 0, 0, 0);
        st[kf] = a;
      }

      const bool edge = (k0 + 63 > qlo);
      float sc[16];
      float tmax = -3e38f;
      #pragma unroll
      for (int kf = 0; kf < 4; kf++)
        #pragma unroll
        for (int r = 0; r < 4; r++){
          float v = st[kf][r];             // RAW (no pre-scale; folded into exp2 fma)
          if (edge && (k0 + kf * 16 + g * 4 + r > qlo + c)) v = -3e38f;
          sc[kf * 4 + r] = v;
          tmax = fmaxf(tmax, v);
        }
      tmax = fmaxf(tmax, __shfl_xor(tmax, 16));
      tmax = fmaxf(tmax, __shfl_xor(tmax, 32));

      // T13: skip rescale when the running max doesn't grow
      if (!__all(tmax <= m_[rt])){
        float mnew = fmaxf(m_[rt], tmax);
        float fe = exp2f((m_[rt] - mnew) * SC);
        m_[rt] = mnew;
        l_[rt] *= fe;
        float feq0 = __shfl(fe, g * 4 + 0), feq1 = __shfl(fe, g * 4 + 1);
        float feq2 = __shfl(fe, g * 4 + 2), feq3 = __shfl(fe, g * 4 + 3);
        #pragma unroll
        for (int nt = 0; nt < 4; nt++){
          f32x4 t = o_acc[rt][nt];
          t[0] *= feq0; t[1] *= feq1; t[2] *= feq2; t[3] *= feq3;
          o_acc[rt][nt] = t;
        }
      }

      const float nmsc = -m_[rt] * SC;
      float rs = 0.f;
      const int prow = rt * 16 + c;
      #pragma unroll
      for (int kf = 0; kf < 4; kf++){
        float p0 = exp2f(fmaf(sc[kf * 4 + 0], SC, nmsc));
        float p1 = exp2f(fmaf(sc[kf * 4 + 1], SC, nmsc));
        float p2 = exp2f(fmaf(sc[kf * 4 + 2], SC, nmsc));
        float p3 = exp2f(fmaf(sc[kf * 4 + 3], SC, nmsc));
        rs += (p0 + p1) + (p2 + p3);
        uint2 pk;
        pk.x = cvt_pk_bf16(p0, p1);
        pk.y = cvt_pk_bf16(p2, p3);
        *(uint2*)&Pw[prow * 64 + ((2 * kf + (g >> 1)) ^ c7) * 8 + (g & 1) * 4] = pk;
      }
      rs += __shfl_xor(rs, 16);
      rs += __shfl_xor(rs, 32);
      l_[rt] += rs;
    }

    s16x8 vb[4][2];
    #pragma unroll
    for (int nt = 0; nt < 4; nt++)
      #pragma unroll
      for (int ks = 0; ks < 2; ks++)
        vb[nt][ks] = *(const s16x8*)&VB[(nt * 16 + c) * 64 + ((ks * 4 + g) ^ c7) * 8];

    #pragma unroll
    for (int rt = 0; rt < 2; rt++){
      if (k0 > q0w + rt * 16 + 15) continue;
      #pragma unroll
      for (int ks = 0; ks < 2; ks++){
        s16x8 pa = *(const s16x8*)&Pw[(rt * 16 + c) * 64 + ((ks * 4 + g) ^ c7) * 8];
        #pragma unroll
        for (int nt = 0; nt < 4; nt++)
          o_acc[rt][nt] = __builtin_amdgcn_mfma_f32_16x16x32_bf16(pa, vb[nt][ks], o_acc[rt][nt], 0, 0, 0);
      }
    }
  };

  // ---- 2-phase main loop: stage(next) || compute(cur) ----
  STAGE(0, 0);
  __syncthreads();
  int cur = 0;
  for (int t = 0; t < nkt; t++){
    if (t + 1 < nkt) STAGE(cur ^ 1, t + 1);
    COMPUTE(cur, t);
    __syncthreads();
    cur ^= 1;
  }

  // ---- epilogue: O / l -> [token][1024] bf16 ----
  const int h = bh & 15, b = bh >> 4;
  #pragma unroll
  for (int rt = 0; rt < 2; rt++){
    float linv = 1.0f / l_[rt];
    float lr0 = __shfl(linv, g * 4 + 0), lr1 = __shfl(linv, g * 4 + 1);
    float lr2 = __shfl(linv, g * 4 + 2), lr3 = __shfl(linv, g * 4 + 3);
    #pragma unroll
    for (int nt = 0; nt < 4; nt++){
      int q = q0w + rt * 16 + g * 4;
      size_t base = (size_t)(b * S_ + q) * D_ + h * HS_ + nt * 16 + c;
      Og[base]            = f2bf(o_acc[rt][nt][0] * lr0);
      Og[base + D_]       = f2bf(o_acc[rt][nt][1] * lr1);
      Og[base + 2 * D_]   = f2bf(o_acc[rt][nt][2] * lr2);
      Og[base + 3 * D_]   = f2bf(o_acc[rt][nt][3] * lr3);
    }
  }
}

extern "C" void kernel_launch(void* const* d_in, const int* in_sizes, int n_in,
                              void* d_out, int out_size, void* d_ws, size_t ws_size,
                              hipStream_t stream)
{
  const float* x    = (const float*)d_in[0];
  const float* Wqkv = (const float*)d_in[1];
  const float* bqkv = (const float*)d_in[2];
  const float* Wout = (const float*)d_in[3];
  const float* bout = (const float*)d_in[4];

  char* ws = (char*)d_ws;
  short* xb     = (short*)(ws);                 //  8 MB [4096][1024] bf16 (reused as O_tok)
  short* Wqkv_t = (short*)(ws + 8388608);       //  6 MB [3072][1024]
  short* Wout_t = (short*)(ws + 14680064);      //  2 MB [1024][1024]
  short* Qg     = (short*)(ws + 16777216);      //  8 MB [32][2048][64]
  short* Kg     = Qg + 4194304;                 //  8 MB
  short* Vg     = Qg + 8388608;                 //  8 MB
  short* Vt     = (short*)(ws + 41943040);      //  8 MB [32][64][2048]
  short* Otok   = xb;                           //  reuse (xb dead after QKV GEMM)

  k_cvt<<<4096, 256, 0, stream>>>(x, xb, TOK * D_ / 4);
  k_tconv<<<dim3(96, 32), 256, 0, stream>>>(Wqkv, Wqkv_t, 1024, 3072);
  k_tconv<<<dim3(32, 32), 256, 0, stream>>>(Wout, Wout_t, 1024, 1024);
  k_gemm_qkv<<<dim3(32, 24), 256, 0, stream>>>(xb, Wqkv_t, bqkv, Qg);
  k_vtrans<<<dim3(32, 32), 256, 0, stream>>>(Vg, Vt);
  k_attn<<<dim3(512), 256, 0, stream>>>(Qg, Kg, Vt, Otok);
  k_gemm_o<<<dim3(64, 8), 256, 0, stream>>>(Otok, Wout_t, bout, (float*)d_out);
}

// Round 12
// 220.835 us; speedup vs baseline: 1.3062x; 1.0046x over previous
//
#include <hip/hip_runtime.h>
#include <hip/hip_bf16.h>
#include <stdint.h>

typedef __attribute__((ext_vector_type(4))) float f32x4;
typedef __attribute__((ext_vector_type(8))) short s16x8;
typedef __attribute__((ext_vector_type(4))) short s16x4;

#define B_   2
#define S_   2048
#define D_   1024
#define H_   16
#define HS_  64
#define TOK  (B_*S_)   // 4096
#define BH_  (B_*H_)   // 32

__device__ __forceinline__ short f2bf(float f){
  union { float f; uint32_t u; } v; v.f = f;
  uint32_t u = v.u;
  u += 0x7fffu + ((u >> 16) & 1u);   // round-to-nearest-even
  return (short)(u >> 16);
}

__device__ __forceinline__ uint32_t cvt_pk_bf16(float lo, float hi){
  uint32_t r;
  asm("v_cvt_pk_bf16_f32 %0, %1, %2" : "=v"(r) : "v"(lo), "v"(hi));
  return r;
}

__device__ __forceinline__ void gload_lds16(const void* g, void* l){
  __builtin_amdgcn_global_load_lds((const __attribute__((address_space(1))) void*)g,
                                   (__attribute__((address_space(3))) void*)l, 16, 0, 0);
}

// ---------------- fp32 -> bf16 convert (vectorized) ----------------
__global__ void k_cvt(const float* __restrict__ src, short* __restrict__ dst, int n4){
  int i = blockIdx.x * blockDim.x + threadIdx.x;
  if (i < n4){
    float4 v = reinterpret_cast<const float4*>(src)[i];
    s16x4 o;
    o.x = f2bf(v.x); o.y = f2bf(v.y); o.z = f2bf(v.z); o.w = f2bf(v.w);
    reinterpret_cast<s16x4*>(dst)[i] = o;
  }
}

// ---------------- transpose + convert: src[K][N] f32 -> dst[N][K] bf16 ----------------
__global__ void k_tconv(const float* __restrict__ src, short* __restrict__ dst, int K, int N){
  __shared__ short tile[32][33];
  const int n0 = blockIdx.x * 32, k0 = blockIdx.y * 32;
  const int c = threadIdx.x & 31, r8 = threadIdx.x >> 5;
  #pragma unroll
  for (int j = 0; j < 4; j++){
    int k = r8 + j * 8;
    tile[c][k] = f2bf(src[(size_t)(k0 + k) * N + n0 + c]);
  }
  __syncthreads();
  #pragma unroll
  for (int j = 0; j < 4; j++){
    int nl = r8 + j * 8;
    dst[(size_t)(n0 + nl) * K + k0 + c] = tile[nl][c];
  }
}

// ---------------- bf16 GEMM, 128x128 tile, BK=32, K=1024 (QKV: EPI scatter) ----------------
__global__ __launch_bounds__(256, 2) void k_gemm_qkv(
    const short* __restrict__ A, const short* __restrict__ Bt,
    const float* __restrict__ bias, short* __restrict__ Qb)
{
  __shared__ short Al[128 * 32];
  __shared__ short Bl[128 * 32];
  const int tid = threadIdx.x;
  const int lane = tid & 63, wave = tid >> 6;
  const int m0 = blockIdx.x * 128, n0 = blockIdx.y * 128;
  const int wm = (wave >> 1) * 64, wn = (wave & 1) * 64;
  const int c = lane & 15, g = lane >> 4;

  f32x4 acc[4][4];
  #pragma unroll
  for (int i = 0; i < 4; i++)
    #pragma unroll
    for (int j = 0; j < 4; j++) acc[i][j] = (f32x4){0.f, 0.f, 0.f, 0.f};

  const short* Asrc = A + (size_t)m0 * 1024;
  const short* Bsrc = Bt + (size_t)n0 * 1024;

  for (int kt = 0; kt < 1024; kt += 32){
    __syncthreads();
    #pragma unroll
    for (int j = 0; j < 2; j++){
      int gc = (wave * 2 + j) * 64 + lane;
      int row = gc >> 2, c8 = gc & 3;
      gload_lds16(Asrc + (size_t)row * 1024 + kt + c8 * 8, Al + (size_t)(wave * 2 + j) * 512);
      gload_lds16(Bsrc + (size_t)row * 1024 + kt + c8 * 8, Bl + (size_t)(wave * 2 + j) * 512);
    }
    __syncthreads();

    s16x8 af[4], bq[4];
    #pragma unroll
    for (int t = 0; t < 4; t++){
      af[t] = *(const s16x8*)&Al[(wm + t * 16 + c) * 32 + g * 8];
      bq[t] = *(const s16x8*)&Bl[(wn + t * 16 + c) * 32 + g * 8];
    }
    #pragma unroll
    for (int mt = 0; mt < 4; mt++)
      #pragma unroll
      for (int nt = 0; nt < 4; nt++)
        acc[mt][nt] = __builtin_amdgcn_mfma_f32_16x16x32_bf16(af[mt], bq[nt], acc[mt][nt], 0, 0, 0);
  }

  const size_t QSZ = (size_t)BH_ * S_ * HS_;
  #pragma unroll
  for (int mt = 0; mt < 4; mt++){
    #pragma unroll
    for (int nt = 0; nt < 4; nt++){
      int n = n0 + wn + nt * 16 + c;
      float bv = bias[n];
      int sel = n >> 10, hn = (n >> 6) & 15, d = n & 63;
      #pragma unroll
      for (int r = 0; r < 4; r++){
        int token = m0 + wm + mt * 16 + g * 4 + r;
        int b = token >> 11, s = token & 2047;
        float v = acc[mt][nt][r] + bv;
        Qb[(size_t)sel * QSZ + ((size_t)(b * H_ + hn) * S_ + s) * HS_ + d] = f2bf(v);
      }
    }
  }
}

// ---------------- out-proj GEMM, 64x128 tile (512 blocks = 2/CU) ----------------
__global__ __launch_bounds__(256, 2) void k_gemm_o(
    const short* __restrict__ A, const short* __restrict__ Bt,
    const float* __restrict__ bias, float* __restrict__ O)
{
  __shared__ short Al[64 * 32];
  __shared__ short Bl[128 * 32];
  const int tid = threadIdx.x;
  const int lane = tid & 63, wave = tid >> 6;
  const int m0 = blockIdx.x * 64, n0 = blockIdx.y * 128;
  const int wn = wave * 32;
  const int c = lane & 15, g = lane >> 4;

  f32x4 acc[4][2];
  #pragma unroll
  for (int i = 0; i < 4; i++)
    #pragma unroll
    for (int j = 0; j < 2; j++) acc[i][j] = (f32x4){0.f, 0.f, 0.f, 0.f};

  const short* Asrc = A + (size_t)m0 * 1024;
  const short* Bsrc = Bt + (size_t)n0 * 1024;

  for (int kt = 0; kt < 1024; kt += 32){
    __syncthreads();
    {
      int gc = wave * 64 + lane;
      int row = gc >> 2, c8 = gc & 3;
      gload_lds16(Asrc + (size_t)row * 1024 + kt + c8 * 8, Al + (size_t)wave * 512);
    }
    #pragma unroll
    for (int j = 0; j < 2; j++){
      int gc = (wave * 2 + j) * 64 + lane;
      int row = gc >> 2, c8 = gc & 3;
      gload_lds16(Bsrc + (size_t)row * 1024 + kt + c8 * 8, Bl + (size_t)(wave * 2 + j) * 512);
    }
    __syncthreads();

    s16x8 af[4], bq[2];
    #pragma unroll
    for (int t = 0; t < 4; t++)
      af[t] = *(const s16x8*)&Al[(t * 16 + c) * 32 + g * 8];
    #pragma unroll
    for (int n = 0; n < 2; n++)
      bq[n] = *(const s16x8*)&Bl[(wn + n * 16 + c) * 32 + g * 8];
    #pragma unroll
    for (int mt = 0; mt < 4; mt++)
      #pragma unroll
      for (int n = 0; n < 2; n++)
        acc[mt][n] = __builtin_amdgcn_mfma_f32_16x16x32_bf16(af[mt], bq[n], acc[mt][n], 0, 0, 0);
  }

  #pragma unroll
  for (int mt = 0; mt < 4; mt++){
    #pragma unroll
    for (int n = 0; n < 2; n++){
      int nn = n0 + wn + n * 16 + c;
      float bv = bias[nn];
      #pragma unroll
      for (int r = 0; r < 4; r++){
        int token = m0 + mt * 16 + g * 4 + r;
        O[(size_t)token * 1024 + nn] = acc[mt][n][r] + bv;
      }
    }
  }
}

// ---------------- V [bh][s][64] -> Vt [bh][64][s] (bf16) ----------------
__global__ void k_vtrans(const short* __restrict__ Vg, short* __restrict__ Vt){
  __shared__ short t[64 * 80];
  const int bh = blockIdx.y;
  const int s0 = blockIdx.x * 64;
  const int tid = threadIdx.x;
  const int r = tid >> 3, c8 = (tid & 7) * 8;
  #pragma unroll
  for (int p = 0; p < 2; p++){
    int ss = r + p * 32;
    s16x8 v = *(const s16x8*)&Vg[((size_t)bh * S_ + s0 + ss) * HS_ + c8];
    #pragma unroll
    for (int i = 0; i < 8; i++) t[(c8 + i) * 80 + ss] = v[i];
  }
  __syncthreads();
  #pragma unroll
  for (int p = 0; p < 2; p++){
    int d = r + p * 32;
    s16x8 v = *(const s16x8*)&t[d * 80 + c8];
    *(s16x8*)&Vt[((size_t)bh * HS_ + d) * S_ + s0 + c8] = v;
  }
}

// ---------------- causal flash attention: 3-deep LDS ring, counted vmcnt ----------------
// T3/T4: stage tile t+2 into ring buf while computing t; per-iter wait is
// vmcnt(4) (own stage only) + raw s_barrier -- prefetch stays in flight across
// barriers (no vmcnt(0) drain, the round-6/8 ~5800cy/iter stall). Buffer reuse
// is >=2 barriers after last read (race-safe).
__global__ __launch_bounds__(256, 2) void k_attn(
    const short* __restrict__ Qg, const short* __restrict__ Kg,
    const short* __restrict__ Vt, short* __restrict__ Og)
{
  __shared__ short Kl[3][64 * 64];   // ring [buf][row=key][chunk], chunk ^ (row&7)
  __shared__ short Vl[3][64 * 64];   // ring [buf][row=d][chunk], same swizzle
  __shared__ short Pl[4][32 * 64];   // per-wave P [row=q][chunk], same swizzle

  const int tid = threadIdx.x, lane = tid & 63, wave = tid >> 6;
  const int c = lane & 15, g = lane >> 4;
  const int c7 = c & 7;

  const int p = blockIdx.x;
  const int qt = (p < 256) ? (15 - (p >> 5)) : ((p - 256) >> 5);
  const int bh = p & 31;
  const int q0 = qt * 128;
  const int q0w = q0 + wave * 32;          // this wave's 32 q-rows
  const int nkt = 2 * qt + 2;              // 64-key tiles
  const size_t basebh = (size_t)bh * S_ * HS_;
  const short* Kb  = Kg + basebh;
  const short* Vtb = Vt + (size_t)bh * HS_ * S_;

  s16x8 qb[2][2];
  #pragma unroll
  for (int rt = 0; rt < 2; rt++)
    #pragma unroll
    for (int h = 0; h < 2; h++)
      qb[rt][h] = *(const s16x8*)&Qg[basebh + (size_t)(q0w + rt * 16 + c) * HS_ + h * 32 + g * 8];

  f32x4 o_acc[2][4];
  #pragma unroll
  for (int rt = 0; rt < 2; rt++)
    #pragma unroll
    for (int nt = 0; nt < 4; nt++) o_acc[rt][nt] = (f32x4){0.f, 0.f, 0.f, 0.f};
  float m_[2] = {-3e38f, -3e38f}, l_[2] = {0.f, 0.f};   // m in RAW S units

  short* Pw = &Pl[wave][0];
  const float SC = 0.125f * 1.44269504f;   // scale * log2(e)

  const int srow = tid >> 3;               // staging rows {srow, srow+32}
  const int schk = tid & 7;
  const int swc  = ((schk ^ (srow & 7)) * 8);  // pre-swizzled source col
  const int ldsoff0 = wave * 512;

  auto STAGE = [&](int buf, int kt){
    const int k0 = kt * 64;
    #pragma unroll
    for (int i = 0; i < 2; i++){
      gload_lds16(Kb + (size_t)(k0 + srow + 32 * i) * HS_ + swc, &Kl[buf][i * 2048 + ldsoff0]);
      gload_lds16(Vtb + (size_t)(srow + 32 * i) * S_ + k0 + swc, &Vl[buf][i * 2048 + ldsoff0]);
    }
  };

  auto COMPUTE = [&](int buf, int kt){
    const int k0 = kt * 64;
    if (k0 > q0w + 31) return;             // all rows masked: idle wave skips work
    const short* KB = &Kl[buf][0];
    const short* VB = &Vl[buf][0];

    s16x8 ka[4][2];
    #pragma unroll
    for (int kf = 0; kf < 4; kf++)
      #pragma unroll
      for (int h = 0; h < 2; h++)
        ka[kf][h] = *(const s16x8*)&KB[(kf * 16 + c) * 64 + ((h * 4 + g) ^ c7) * 8];

    #pragma unroll
    for (int rt = 0; rt < 2; rt++){
      const int qlo = q0w + rt * 16;
      if (k0 > qlo + 15) continue;

      f32x4 st[4];
      __builtin_amdgcn_s_setprio(1);
      #pragma unroll
      for (int kf = 0; kf < 4; kf++){
        f32x4 a = (f32x4){0.f, 0.f, 0.f, 0.f};
        a = __builtin_amdgcn_mfma_f32_16x16x32_bf16(ka[kf][0], qb[rt][0], a, 0, 0, 0);
        a = __builtin_amdgcn_mfma_f32_16x16x32_bf16(ka[kf][1], qb[rt][1], a, 0, 0, 0);
        st[kf] = a;
      }
      __builtin_amdgcn_s_setprio(0);

      const bool edge = (k0 + 63 > qlo);
      float sc[16];
      float tmax = -3e38f;
      #pragma unroll
      for (int kf = 0; kf < 4; kf++)
        #pragma unroll
        for (int r = 0; r < 4; r++){
          float v = st[kf][r];
          if (edge && (k0 + kf * 16 + g * 4 + r > qlo + c)) v = -3e38f;
          sc[kf * 4 + r] = v;
          tmax = fmaxf(tmax, v);
        }
      tmax = fmaxf(tmax, __shfl_xor(tmax, 16));
      tmax = fmaxf(tmax, __shfl_xor(tmax, 32));

      if (!__all(tmax <= m_[rt])){
        float mnew = fmaxf(m_[rt], tmax);
        float fe = exp2f((m_[rt] - mnew) * SC);
        m_[rt] = mnew;
        l_[rt] *= fe;
        float feq0 = __shfl(fe, g * 4 + 0), feq1 = __shfl(fe, g * 4 + 1);
        float feq2 = __shfl(fe, g * 4 + 2), feq3 = __shfl(fe, g * 4 + 3);
        #pragma unroll
        for (int nt = 0; nt < 4; nt++){
          f32x4 t = o_acc[rt][nt];
          t[0] *= feq0; t[1] *= feq1; t[2] *= feq2; t[3] *= feq3;
          o_acc[rt][nt] = t;
        }
      }

      const float nmsc = -m_[rt] * SC;
      float rs = 0.f;
      const int prow = rt * 16 + c;
      #pragma unroll
      for (int kf = 0; kf < 4; kf++){
        float p0 = exp2f(fmaf(sc[kf * 4 + 0], SC, nmsc));
        float p1 = exp2f(fmaf(sc[kf * 4 + 1], SC, nmsc));
        float p2 = exp2f(fmaf(sc[kf * 4 + 2], SC, nmsc));
        float p3 = exp2f(fmaf(sc[kf * 4 + 3], SC, nmsc));
        rs += (p0 + p1) + (p2 + p3);
        uint2 pk;
        pk.x = cvt_pk_bf16(p0, p1);
        pk.y = cvt_pk_bf16(p2, p3);
        *(uint2*)&Pw[prow * 64 + ((2 * kf + (g >> 1)) ^ c7) * 8 + (g & 1) * 4] = pk;
      }
      rs += __shfl_xor(rs, 16);
      rs += __shfl_xor(rs, 32);
      l_[rt] += rs;
    }

    s16x8 vb[4][2];
    #pragma unroll
    for (int nt = 0; nt < 4; nt++)
      #pragma unroll
      for (int ks = 0; ks < 2; ks++)
        vb[nt][ks] = *(const s16x8*)&VB[(nt * 16 + c) * 64 + ((ks * 4 + g) ^ c7) * 8];

    __builtin_amdgcn_s_setprio(1);
    #pragma unroll
    for (int rt = 0; rt < 2; rt++){
      if (k0 > q0w + rt * 16 + 15) continue;
      #pragma unroll
      for (int ks = 0; ks < 2; ks++){
        s16x8 pa = *(const s16x8*)&Pw[(rt * 16 + c) * 64 + ((ks * 4 + g) ^ c7) * 8];
        #pragma unroll
        for (int nt = 0; nt < 4; nt++)
          o_acc[rt][nt] = __builtin_amdgcn_mfma_f32_16x16x32_bf16(pa, vb[nt][ks], o_acc[rt][nt], 0, 0, 0);
      }
    }
    __builtin_amdgcn_s_setprio(0);
  };

  // ---- main loop: ring-3, prefetch depth 2, counted vmcnt, raw barriers ----
  STAGE(0, 0);
  STAGE(1, 1);                             // nkt >= 2 always
  int cur = 0, stg = 2;
  for (int t = 0; t < nkt; t++){
    if (t < nkt - 1) asm volatile("s_waitcnt vmcnt(4)" ::: "memory");
    else             asm volatile("s_waitcnt vmcnt(0)" ::: "memory");
    __builtin_amdgcn_s_barrier();          // buf(cur) ready for all waves
    asm volatile("" ::: "memory");
    COMPUTE(cur, t);
    asm volatile("" ::: "memory");
    __builtin_amdgcn_s_barrier();          // all waves done reading buf(cur)
    asm volatile("" ::: "memory");
    if (t + 2 < nkt) STAGE(stg, t + 2);
    cur = (cur == 2) ? 0 : cur + 1;
    stg = (stg == 2) ? 0 : stg + 1;
  }

  // ---- epilogue: O / l -> [token][1024] bf16 ----
  const int h = bh & 15, b = bh >> 4;
  #pragma unroll
  for (int rt = 0; rt < 2; rt++){
    float linv = 1.0f / l_[rt];
    float lr0 = __shfl(linv, g * 4 + 0), lr1 = __shfl(linv, g * 4 + 1);
    float lr2 = __shfl(linv, g * 4 + 2), lr3 = __shfl(linv, g * 4 + 3);
    #pragma unroll
    for (int nt = 0; nt < 4; nt++){
      int q = q0w + rt * 16 + g * 4;
      size_t base = (size_t)(b * S_ + q) * D_ + h * HS_ + nt * 16 + c;
      Og[base]            = f2bf(o_acc[rt][nt][0] * lr0);
      Og[base + D_]       = f2bf(o_acc[rt][nt][1] * lr1);
      Og[base + 2 * D_]   = f2bf(o_acc[rt][nt][2] * lr2);
      Og[base + 3 * D_]   = f2bf(o_acc[rt][nt][3] * lr3);
    }
  }
}

extern "C" void kernel_launch(void* const* d_in, const int* in_sizes, int n_in,
                              void* d_out, int out_size, void* d_ws, size_t ws_size,
                              hipStream_t stream)
{
  const float* x    = (const float*)d_in[0];
  const float* Wqkv = (const float*)d_in[1];
  const float* bqkv = (const float*)d_in[2];
  const float* Wout = (const float*)d_in[3];
  const float* bout = (const float*)d_in[4];

  char* ws = (char*)d_ws;
  short* xb     = (short*)(ws);                 //  8 MB [4096][1024] bf16 (reused as O_tok)
  short* Wqkv_t = (short*)(ws + 8388608);       //  6 MB [3072][1024]
  short* Wout_t = (short*)(ws + 14680064);      //  2 MB [1024][1024]
  short* Qg     = (short*)(ws + 16777216);      //  8 MB [32][2048][64]
  short* Kg     = Qg + 4194304;                 //  8 MB
  short* Vg     = Qg + 8388608;                 //  8 MB
  short* Vt     = (short*)(ws + 41943040);      //  8 MB [32][64][2048]
  short* Otok   = xb;                           //  reuse (xb dead after QKV GEMM)

  k_cvt<<<4096, 256, 0, stream>>>(x, xb, TOK * D_ / 4);
  k_tconv<<<dim3(96, 32), 256, 0, stream>>>(Wqkv, Wqkv_t, 1024, 3072);
  k_tconv<<<dim3(32, 32), 256, 0, stream>>>(Wout, Wout_t, 1024, 1024);
  k_gemm_qkv<<<dim3(32, 24), 256, 0, stream>>>(xb, Wqkv_t, bqkv, Qg);
  k_vtrans<<<dim3(32, 32), 256, 0, stream>>>(Vg, Vt);
  k_attn<<<dim3(512), 256, 0, stream>>>(Qg, Kg, Vt, Otok);
  k_gemm_o<<<dim3(64, 8), 256, 0, stream>>>(Otok, Wout_t, bout, (float*)d_out);
}

// Round 13
// 195.750 us; speedup vs baseline: 1.4736x; 1.1281x over previous
//
#include <hip/hip_runtime.h>
#include <hip/hip_bf16.h>
#include <stdint.h>

typedef __attribute__((ext_vector_type(4))) float f32x4;
typedef __attribute__((ext_vector_type(8))) short s16x8;
typedef __attribute__((ext_vector_type(4))) short s16x4;

#define B_   2
#define S_   2048
#define D_   1024
#define H_   16
#define HS_  64
#define TOK  (B_*S_)   // 4096
#define BH_  (B_*H_)   // 32

__device__ __forceinline__ short f2bf(float f){
  union { float f; uint32_t u; } v; v.f = f;
  uint32_t u = v.u;
  u += 0x7fffu + ((u >> 16) & 1u);   // round-to-nearest-even
  return (short)(u >> 16);
}

__device__ __forceinline__ uint32_t cvt_pk_bf16(float lo, float hi){
  uint32_t r;
  asm("v_cvt_pk_bf16_f32 %0, %1, %2" : "=v"(r) : "v"(lo), "v"(hi));
  return r;
}

__device__ __forceinline__ void gload_lds16(const void* g, void* l){
  __builtin_amdgcn_global_load_lds((const __attribute__((address_space(1))) void*)g,
                                   (__attribute__((address_space(3))) void*)l, 16, 0, 0);
}

// ---------------- fp32 -> bf16 convert (vectorized) ----------------
__global__ void k_cvt(const float* __restrict__ src, short* __restrict__ dst, int n4){
  int i = blockIdx.x * blockDim.x + threadIdx.x;
  if (i < n4){
    float4 v = reinterpret_cast<const float4*>(src)[i];
    s16x4 o;
    o.x = f2bf(v.x); o.y = f2bf(v.y); o.z = f2bf(v.z); o.w = f2bf(v.w);
    reinterpret_cast<s16x4*>(dst)[i] = o;
  }
}

// ---------------- transpose + convert: src[K][N] f32 -> dst[N][K] bf16 ----------------
__global__ void k_tconv(const float* __restrict__ src, short* __restrict__ dst, int K, int N){
  __shared__ short tile[32][33];
  const int n0 = blockIdx.x * 32, k0 = blockIdx.y * 32;
  const int c = threadIdx.x & 31, r8 = threadIdx.x >> 5;
  #pragma unroll
  for (int j = 0; j < 4; j++){
    int k = r8 + j * 8;
    tile[c][k] = f2bf(src[(size_t)(k0 + k) * N + n0 + c]);
  }
  __syncthreads();
  #pragma unroll
  for (int j = 0; j < 4; j++){
    int nl = r8 + j * 8;
    dst[(size_t)(n0 + nl) * K + k0 + c] = tile[nl][c];
  }
}

// ---------------- bf16 GEMM, 128x128 tile, BK=32, K=1024 (QKV: EPI scatter) ----------------
__global__ __launch_bounds__(256, 2) void k_gemm_qkv(
    const short* __restrict__ A, const short* __restrict__ Bt,
    const float* __restrict__ bias, short* __restrict__ Qb)
{
  __shared__ short Al[128 * 32];
  __shared__ short Bl[128 * 32];
  const int tid = threadIdx.x;
  const int lane = tid & 63, wave = tid >> 6;
  const int m0 = blockIdx.x * 128, n0 = blockIdx.y * 128;
  const int wm = (wave >> 1) * 64, wn = (wave & 1) * 64;
  const int c = lane & 15, g = lane >> 4;

  f32x4 acc[4][4];
  #pragma unroll
  for (int i = 0; i < 4; i++)
    #pragma unroll
    for (int j = 0; j < 4; j++) acc[i][j] = (f32x4){0.f, 0.f, 0.f, 0.f};

  const short* Asrc = A + (size_t)m0 * 1024;
  const short* Bsrc = Bt + (size_t)n0 * 1024;

  for (int kt = 0; kt < 1024; kt += 32){
    __syncthreads();
    #pragma unroll
    for (int j = 0; j < 2; j++){
      int gc = (wave * 2 + j) * 64 + lane;
      int row = gc >> 2, c8 = gc & 3;
      gload_lds16(Asrc + (size_t)row * 1024 + kt + c8 * 8, Al + (size_t)(wave * 2 + j) * 512);
      gload_lds16(Bsrc + (size_t)row * 1024 + kt + c8 * 8, Bl + (size_t)(wave * 2 + j) * 512);
    }
    __syncthreads();

    s16x8 af[4], bq[4];
    #pragma unroll
    for (int t = 0; t < 4; t++){
      af[t] = *(const s16x8*)&Al[(wm + t * 16 + c) * 32 + g * 8];
      bq[t] = *(const s16x8*)&Bl[(wn + t * 16 + c) * 32 + g * 8];
    }
    #pragma unroll
    for (int mt = 0; mt < 4; mt++)
      #pragma unroll
      for (int nt = 0; nt < 4; nt++)
        acc[mt][nt] = __builtin_amdgcn_mfma_f32_16x16x32_bf16(af[mt], bq[nt], acc[mt][nt], 0, 0, 0);
  }

  const size_t QSZ = (size_t)BH_ * S_ * HS_;
  #pragma unroll
  for (int mt = 0; mt < 4; mt++){
    #pragma unroll
    for (int nt = 0; nt < 4; nt++){
      int n = n0 + wn + nt * 16 + c;
      float bv = bias[n];
      int sel = n >> 10, hn = (n >> 6) & 15, d = n & 63;
      #pragma unroll
      for (int r = 0; r < 4; r++){
        int token = m0 + wm + mt * 16 + g * 4 + r;
        int b = token >> 11, s = token & 2047;
        float v = acc[mt][nt][r] + bv;
        Qb[(size_t)sel * QSZ + ((size_t)(b * H_ + hn) * S_ + s) * HS_ + d] = f2bf(v);
      }
    }
  }
}

// ---------------- out-proj GEMM, 64x128 tile (512 blocks = 2/CU) ----------------
__global__ __launch_bounds__(256, 2) void k_gemm_o(
    const short* __restrict__ A, const short* __restrict__ Bt,
    const float* __restrict__ bias, float* __restrict__ O)
{
  __shared__ short Al[64 * 32];
  __shared__ short Bl[128 * 32];
  const int tid = threadIdx.x;
  const int lane = tid & 63, wave = tid >> 6;
  const int m0 = blockIdx.x * 64, n0 = blockIdx.y * 128;
  const int wn = wave * 32;
  const int c = lane & 15, g = lane >> 4;

  f32x4 acc[4][2];
  #pragma unroll
  for (int i = 0; i < 4; i++)
    #pragma unroll
    for (int j = 0; j < 2; j++) acc[i][j] = (f32x4){0.f, 0.f, 0.f, 0.f};

  const short* Asrc = A + (size_t)m0 * 1024;
  const short* Bsrc = Bt + (size_t)n0 * 1024;

  for (int kt = 0; kt < 1024; kt += 32){
    __syncthreads();
    {
      int gc = wave * 64 + lane;
      int row = gc >> 2, c8 = gc & 3;
      gload_lds16(Asrc + (size_t)row * 1024 + kt + c8 * 8, Al + (size_t)wave * 512);
    }
    #pragma unroll
    for (int j = 0; j < 2; j++){
      int gc = (wave * 2 + j) * 64 + lane;
      int row = gc >> 2, c8 = gc & 3;
      gload_lds16(Bsrc + (size_t)row * 1024 + kt + c8 * 8, Bl + (size_t)(wave * 2 + j) * 512);
    }
    __syncthreads();

    s16x8 af[4], bq[2];
    #pragma unroll
    for (int t = 0; t < 4; t++)
      af[t] = *(const s16x8*)&Al[(t * 16 + c) * 32 + g * 8];
    #pragma unroll
    for (int n = 0; n < 2; n++)
      bq[n] = *(const s16x8*)&Bl[(wn + n * 16 + c) * 32 + g * 8];
    #pragma unroll
    for (int mt = 0; mt < 4; mt++)
      #pragma unroll
      for (int n = 0; n < 2; n++)
        acc[mt][n] = __builtin_amdgcn_mfma_f32_16x16x32_bf16(af[mt], bq[n], acc[mt][n], 0, 0, 0);
  }

  #pragma unroll
  for (int mt = 0; mt < 4; mt++){
    #pragma unroll
    for (int n = 0; n < 2; n++){
      int nn = n0 + wn + n * 16 + c;
      float bv = bias[nn];
      #pragma unroll
      for (int r = 0; r < 4; r++){
        int token = m0 + mt * 16 + g * 4 + r;
        O[(size_t)token * 1024 + nn] = acc[mt][n][r] + bv;
      }
    }
  }
}

// ---------------- V [bh][s][64] -> Vt [bh][64][s] (bf16) ----------------
__global__ void k_vtrans(const short* __restrict__ Vg, short* __restrict__ Vt){
  __shared__ short t[64 * 80];
  const int bh = blockIdx.y;
  const int s0 = blockIdx.x * 64;
  const int tid = threadIdx.x;
  const int r = tid >> 3, c8 = (tid & 7) * 8;
  #pragma unroll
  for (int p = 0; p < 2; p++){
    int ss = r + p * 32;
    s16x8 v = *(const s16x8*)&Vg[((size_t)bh * S_ + s0 + ss) * HS_ + c8];
    #pragma unroll
    for (int i = 0; i < 8; i++) t[(c8 + i) * 80 + ss] = v[i];
  }
  __syncthreads();
  #pragma unroll
  for (int p = 0; p < 2; p++){
    int d = r + p * 32;
    s16x8 v = *(const s16x8*)&t[d * 80 + c8];
    *(s16x8*)&Vt[((size_t)bh * HS_ + d) * S_ + s0 + c8] = v;
  }
}

// ---------------- causal flash attention: 64-q blocks, 16 waves/CU ----------------
// Round-12 falsified latency theories; counters show dependency-latency bind at
// 8 waves/CU (VALU 34%, MFMA 8%). Fix = concurrency: 64-q blocks (4 waves x 16
// rows), ring-2 K/V (32KB) + P (8KB) = 40KB LDS, VGPR<=128 -> 4 blocks/CU = 16
// waves/CU. Every wave active every iter; 1 barrier/iter; own-wave vmcnt(0)
// (prefetch issued a full compute phase earlier). Co-resident quads {j,j+8,
// j+16,j+24} have qt sums == 62 -> balanced 66 iters/CU.
__global__ __launch_bounds__(256, 4) void k_attn(
    const short* __restrict__ Qg, const short* __restrict__ Kg,
    const short* __restrict__ Vt, short* __restrict__ Og)
{
  __shared__ short Kl[2][64 * 64];   // ring [buf][row=key][chunk], chunk ^ (row&7)
  __shared__ short Vl[2][64 * 64];   // ring [buf][row=d][chunk], same swizzle
  __shared__ short Pl[4][16 * 64];   // per-wave P [row=q][chunk], same swizzle

  const int tid = threadIdx.x, lane = tid & 63, wave = tid >> 6;
  const int c = lane & 15, g = lane >> 4;
  const int c7 = c & 7;

  const int p = blockIdx.x;
  const int j = p >> 5, bh = p & 31;
  const int grp = j >> 3;
  const int qt = (grp == 0 || grp == 2) ? (31 - j) : ((grp == 1) ? (j + 8) : (j - 24));
  const int q0 = qt * 64;
  const int q0w = q0 + wave * 16;          // this wave's 16 q-rows
  const int nkt = qt + 1;                  // 64-key tiles
  const size_t basebh = (size_t)bh * S_ * HS_;
  const short* Kb  = Kg + basebh;
  const short* Vtb = Vt + (size_t)bh * HS_ * S_;

  // Q fragments: qb[h] = Q[q0w + c][h*32 + g*8 ..+7]
  s16x8 qb0, qb1;
  {
    const short* qp = Qg + basebh + (size_t)(q0w + c) * HS_ + g * 8;
    qb0 = *(const s16x8*)qp;
    qb1 = *(const s16x8*)(qp + 32);
  }
  f32x4 o_acc[4];
  #pragma unroll
  for (int nt = 0; nt < 4; nt++) o_acc[nt] = (f32x4){0.f, 0.f, 0.f, 0.f};
  float m_ = -3e38f, l_ = 0.f;             // m in RAW S units

  short* Pw = &Pl[wave][0];
  const float SC = 0.125f * 1.44269504f;   // scale * log2(e)

  const int srow = tid >> 3;               // staging rows {srow, srow+32}
  const int schk = tid & 7;
  const int swc  = ((schk ^ (srow & 7)) * 8);  // pre-swizzled source col
  const int ldsoff0 = wave * 512;

  auto STAGE = [&](int buf, int kt){
    const int k0 = kt * 64;
    #pragma unroll
    for (int i = 0; i < 2; i++){
      gload_lds16(Kb + (size_t)(k0 + srow + 32 * i) * HS_ + swc, &Kl[buf][i * 2048 + ldsoff0]);
      gload_lds16(Vtb + (size_t)(srow + 32 * i) * S_ + k0 + swc, &Vl[buf][i * 2048 + ldsoff0]);
    }
  };

  auto COMPUTE = [&](int buf, int kt){
    const int k0 = kt * 64;
    const short* KB = &Kl[buf][0];
    const short* VB = &Vl[buf][0];

    // K fragments (swizzled ds_read_b128)
    s16x8 ka[4][2];
    #pragma unroll
    for (int kf = 0; kf < 4; kf++)
      #pragma unroll
      for (int h = 0; h < 2; h++)
        ka[kf][h] = *(const s16x8*)&KB[(kf * 16 + c) * 64 + ((h * 4 + g) ^ c7) * 8];

    // S^T: st[kf][r] = S[q0w + c][k0 + kf*16 + g*4 + r]
    f32x4 st[4];
    __builtin_amdgcn_s_setprio(1);
    #pragma unroll
    for (int kf = 0; kf < 4; kf++){
      f32x4 a = (f32x4){0.f, 0.f, 0.f, 0.f};
      a = __builtin_amdgcn_mfma_f32_16x16x32_bf16(ka[kf][0], qb0, a, 0, 0, 0);
      a = __builtin_amdgcn_mfma_f32_16x16x32_bf16(ka[kf][1], qb1, a, 0, 0, 0);
      st[kf] = a;
    }
    __builtin_amdgcn_s_setprio(0);

    const bool edge = (k0 + 63 > q0w);     // only the final tile
    float sc[16];
    float tmax = -3e38f;
    #pragma unroll
    for (int kf = 0; kf < 4; kf++)
      #pragma unroll
      for (int r = 0; r < 4; r++){
        float v = st[kf][r];               // RAW; scale folded into exp2 fma
        if (edge && (k0 + kf * 16 + g * 4 + r > q0w + c)) v = -3e38f;
        sc[kf * 4 + r] = v;
        tmax = fmaxf(tmax, v);
      }
    tmax = fmaxf(tmax, __shfl_xor(tmax, 16));
    tmax = fmaxf(tmax, __shfl_xor(tmax, 32));

    // T13: skip rescale when running max doesn't grow (wave-uniform)
    if (!__all(tmax <= m_)){
      float mnew = fmaxf(m_, tmax);
      float fe = exp2f((m_ - mnew) * SC);
      m_ = mnew;
      l_ *= fe;
      float feq0 = __shfl(fe, g * 4 + 0), feq1 = __shfl(fe, g * 4 + 1);
      float feq2 = __shfl(fe, g * 4 + 2), feq3 = __shfl(fe, g * 4 + 3);
      #pragma unroll
      for (int nt = 0; nt < 4; nt++){
        f32x4 t = o_acc[nt];
        t[0] *= feq0; t[1] *= feq1; t[2] *= feq2; t[3] *= feq3;
        o_acc[nt] = t;
      }
    }

    const float nmsc = -m_ * SC;
    float rs = 0.f;
    #pragma unroll
    for (int kf = 0; kf < 4; kf++){
      float p0 = exp2f(fmaf(sc[kf * 4 + 0], SC, nmsc));
      float p1 = exp2f(fmaf(sc[kf * 4 + 1], SC, nmsc));
      float p2 = exp2f(fmaf(sc[kf * 4 + 2], SC, nmsc));
      float p3 = exp2f(fmaf(sc[kf * 4 + 3], SC, nmsc));
      rs += (p0 + p1) + (p2 + p3);
      uint2 pk;
      pk.x = cvt_pk_bf16(p0, p1);
      pk.y = cvt_pk_bf16(p2, p3);
      *(uint2*)&Pw[c * 64 + ((2 * kf + (g >> 1)) ^ c7) * 8 + (g & 1) * 4] = pk;
    }
    rs += __shfl_xor(rs, 16);
    rs += __shfl_xor(rs, 32);
    l_ += rs;

    // PV
    s16x8 vb[4][2];
    #pragma unroll
    for (int nt = 0; nt < 4; nt++)
      #pragma unroll
      for (int ks = 0; ks < 2; ks++)
        vb[nt][ks] = *(const s16x8*)&VB[(nt * 16 + c) * 64 + ((ks * 4 + g) ^ c7) * 8];

    __builtin_amdgcn_s_setprio(1);
    #pragma unroll
    for (int ks = 0; ks < 2; ks++){
      s16x8 pa = *(const s16x8*)&Pw[c * 64 + ((ks * 4 + g) ^ c7) * 8];
      #pragma unroll
      for (int nt = 0; nt < 4; nt++)
        o_acc[nt] = __builtin_amdgcn_mfma_f32_16x16x32_bf16(pa, vb[nt][ks], o_acc[nt], 0, 0, 0);
    }
    __builtin_amdgcn_s_setprio(0);
  };

  // ---- main loop: ring-2, 1 barrier/iter, own-wave vmcnt(0) ----
  STAGE(0, 0);
  int cur = 0;
  for (int t = 0; t < nkt; t++){
    asm volatile("s_waitcnt vmcnt(0)" ::: "memory");   // own 4 loads for tile t
    __builtin_amdgcn_s_barrier();                      // all waves staged tile t;
    asm volatile("" ::: "memory");                     // also fences prev compute reads
    if (t + 1 < nkt) STAGE(cur ^ 1, t + 1);            // hidden under COMPUTE(t)
    COMPUTE(cur, t);
    cur ^= 1;
  }

  // ---- epilogue: O / l -> [token][1024] bf16 ----
  const int h = bh & 15, b = bh >> 4;
  float linv = 1.0f / l_;
  float lr0 = __shfl(linv, g * 4 + 0), lr1 = __shfl(linv, g * 4 + 1);
  float lr2 = __shfl(linv, g * 4 + 2), lr3 = __shfl(linv, g * 4 + 3);
  #pragma unroll
  for (int nt = 0; nt < 4; nt++){
    int q = q0w + g * 4;
    size_t base = (size_t)(b * S_ + q) * D_ + h * HS_ + nt * 16 + c;
    Og[base]          = f2bf(o_acc[nt][0] * lr0);
    Og[base + D_]     = f2bf(o_acc[nt][1] * lr1);
    Og[base + 2 * D_] = f2bf(o_acc[nt][2] * lr2);
    Og[base + 3 * D_] = f2bf(o_acc[nt][3] * lr3);
  }
}

extern "C" void kernel_launch(void* const* d_in, const int* in_sizes, int n_in,
                              void* d_out, int out_size, void* d_ws, size_t ws_size,
                              hipStream_t stream)
{
  const float* x    = (const float*)d_in[0];
  const float* Wqkv = (const float*)d_in[1];
  const float* bqkv = (const float*)d_in[2];
  const float* Wout = (const float*)d_in[3];
  const float* bout = (const float*)d_in[4];

  char* ws = (char*)d_ws;
  short* xb     = (short*)(ws);                 //  8 MB [4096][1024] bf16 (reused as O_tok)
  short* Wqkv_t = (short*)(ws + 8388608);       //  6 MB [3072][1024]
  short* Wout_t = (short*)(ws + 14680064);      //  2 MB [1024][1024]
  short* Qg     = (short*)(ws + 16777216);      //  8 MB [32][2048][64]
  short* Kg     = Qg + 4194304;                 //  8 MB
  short* Vg     = Qg + 8388608;                 //  8 MB
  short* Vt     = (short*)(ws + 41943040);      //  8 MB [32][64][2048]
  short* Otok   = xb;                           //  reuse (xb dead after QKV GEMM)

  k_cvt<<<4096, 256, 0, stream>>>(x, xb, TOK * D_ / 4);
  k_tconv<<<dim3(96, 32), 256, 0, stream>>>(Wqkv, Wqkv_t, 1024, 3072);
  k_tconv<<<dim3(32, 32), 256, 0, stream>>>(Wout, Wout_t, 1024, 1024);
  k_gemm_qkv<<<dim3(32, 24), 256, 0, stream>>>(xb, Wqkv_t, bqkv, Qg);
  k_vtrans<<<dim3(32, 32), 256, 0, stream>>>(Vg, Vt);
  k_attn<<<dim3(1024), 256, 0, stream>>>(Qg, Kg, Vt, Otok);
  k_gemm_o<<<dim3(64, 8), 256, 0, stream>>>(Otok, Wout_t, bout, (float*)d_out);
}